// Round 2
// baseline (3642.229 us; speedup 1.0000x reference)
//
#include <hip/hip_runtime.h>

// ---------------------------------------------------------------------------
// AttentionDecoder: B=64 T=32 S=64 H=1024 V=32000
// R2: persistent-kernel recurrence (1 launch, hand-rolled grid barrier)
//  - prep: split weights to bf16 hi/lo, encT = enc@l1 (split GEMM),
//          embi = embx @ w_ih[:, :1024]^T  (batched, hoisted out of the loop)
//  - k_rec (192 blocks, resident): per step t:
//      P1: gi_ctx (dctx@wih2^T) + gh (h@whh^T), 192 split-K 64x64 jobs
//      bar
//      P2: 64 blocks: reduce gates + GRU -> h, scores vs encT (f32),
//          mask+softmax, ctx=attn@enc, cat=[ctx,h] hi/lo, attn out
//      bar
//      P3: 16 blocks: cat@l2^T full-K 64x64 + tanh -> dctx[t+1] hi/lo
//      bar
//  - logits GEMM (2048x32000,K=1024) bf16 MFMA + bias -> d_out
//  - k_lsm in-place log-softmax
// Split-bf16 (hi/lo, 3-term MFMA) keeps recurrence ~f32-accurate (attention
// threshold ~0.0245 requires it).
// ---------------------------------------------------------------------------

#define B_ 64
#define T_ 32
#define S_ 64
#define H_ 1024
#define V_ 32000
#define NB_ 192

#define HID_OFF 65536000L
#define ATT_OFF 65601536L
#define CTF_OFF 65732608L

typedef __attribute__((ext_vector_type(8))) short bf16x8;
typedef __attribute__((ext_vector_type(4))) float f32x4;
typedef __attribute__((ext_vector_type(4))) unsigned int u32x4;
typedef unsigned short u16;

__device__ __forceinline__ u16 f2bf(float v) {
  unsigned int u = __float_as_uint(v);
  unsigned int r = (u + 0x7fffu + ((u >> 16) & 1u)) >> 16;  // RNE
  return (u16)r;
}
__device__ __forceinline__ float bf2f(u16 h) {
  return __uint_as_float(((unsigned int)h) << 16);
}
__device__ __forceinline__ void split2(float v, u16* hi, u16* lo) {
  u16 h = f2bf(v);
  *hi = h;
  *lo = f2bf(v - bf2f(h));
}

// ---------------- conversion / prep kernels ----------------

__global__ void k_split(const float* __restrict__ src, u16* __restrict__ hi,
                        u16* __restrict__ lo, int n) {
  int i = blockIdx.x * blockDim.x + threadIdx.x;
  int stride = gridDim.x * blockDim.x;
  for (; i < n; i += stride) split2(src[i], &hi[i], &lo[i]);
}

__global__ void k_tobf(const float* __restrict__ src, u16* __restrict__ dst, int n) {
  int i = blockIdx.x * blockDim.x + threadIdx.x;
  int stride = gridDim.x * blockDim.x;
  for (; i < n; i += stride) dst[i] = f2bf(src[i]);
}

// l1 (H,H) row-major [i][k] -> l1T hi/lo [k][i]
__global__ void k_l1t(const float* __restrict__ l1, u16* __restrict__ hi,
                      u16* __restrict__ lo) {
  __shared__ float tile[64][65];
  int it = blockIdx.x & 15, kt = blockIdx.x >> 4;
  for (int q = 0; q < 16; ++q) {
    int idx = q * 256 + threadIdx.x;
    int r = idx >> 6, c = idx & 63;
    tile[r][c] = l1[(long)(it * 64 + r) * H_ + kt * 64 + c];
  }
  __syncthreads();
  for (int q = 0; q < 16; ++q) {
    int idx = q * 256 + threadIdx.x;
    int r = idx >> 6, c = idx & 63;
    long o = (long)(kt * 64 + r) * H_ + it * 64 + c;
    split2(tile[c][r], &hi[o], &lo[o]);
  }
}

// gather embeddings: embx[t][b][k] hi/lo
__global__ void k_embx(const int* __restrict__ inp, const float* __restrict__ emb,
                       u16* __restrict__ hi, u16* __restrict__ lo) {
  int bt = blockIdx.x;
  int b = bt >> 5, t = bt & 31;
  int id = inp[b * T_ + t];
  const float* src = emb + (long)id * H_;
  long base = (long)(t * B_ + b) * H_;
  for (int k = threadIdx.x; k < H_; k += 256) split2(src[k], &hi[base + k], &lo[base + k]);
}

__global__ void k_h0(const float* __restrict__ mem, float* __restrict__ hf,
                     u16* __restrict__ hh, u16* __restrict__ hl) {
  int i = blockIdx.x * 256 + threadIdx.x;  // 65536
  float v = mem[i];
  hf[i] = v;
  split2(v, &hh[i], &hl[i]);
}

__global__ void k_guard(float* out, float v) {
  if (blockIdx.x == 0 && threadIdx.x == 0) out[0] = v;
}

// ---------------- 128x128 tile GEMM (BK=32), optional split-bf16 ----------------
template <int SPLIT, int OMODE>
__launch_bounds__(256)
__global__ void k_gemm128(const u16* __restrict__ Ah, const u16* __restrict__ Al,
                          const u16* __restrict__ Bh, const u16* __restrict__ Bl,
                          float* __restrict__ C, const float* __restrict__ bias,
                          int Mtiles, int Ntiles, int K, int Arow, int Brow, int Crow) {
  (void)Ntiles;
  int bx = blockIdx.x;
  int mt = bx % Mtiles, nt = bx / Mtiles;
  int m0 = mt * 128, n0 = nt * 128;

  __shared__ __attribute__((aligned(16))) u16 lds[(SPLIT ? 4 : 2) * 4096];
  char* L = (char*)lds;
  const int tid = threadIdx.x;
  const int lane = tid & 63, wid = tid >> 6;
  const int wm = wid & 1, wn = wid >> 1;
  const int l15 = lane & 15, kq = lane >> 4;

  f32x4 acc[4][4];
  const f32x4 z4 = {0.f, 0.f, 0.f, 0.f};
#pragma unroll
  for (int i = 0; i < 4; ++i)
#pragma unroll
    for (int j = 0; j < 4; ++j) acc[i][j] = z4;

  const int ksteps = K >> 5;
  for (int kt = 0; kt < ksteps; ++kt) {
    __syncthreads();
#pragma unroll
    for (int h2 = 0; h2 < 2; ++h2) {
      int r = (tid >> 2) + (h2 << 6);
      int slot = tid & 3;
      int so = ((slot ^ (r & 3)) << 4);
      long ga = (long)(m0 + r) * Arow + (kt << 5) + (slot << 3);
      long gb = (long)(n0 + r) * Brow + (kt << 5) + (slot << 3);
      *(u32x4*)(L + r * 64 + so) = *(const u32x4*)(Ah + ga);
      *(u32x4*)(L + 8192 + r * 64 + so) = *(const u32x4*)(Bh + gb);
      if (SPLIT) {
        *(u32x4*)(L + 16384 + r * 64 + so) = *(const u32x4*)(Al + ga);
        *(u32x4*)(L + 24576 + r * 64 + so) = *(const u32x4*)(Bl + gb);
      }
    }
    __syncthreads();
    bf16x8 aH[4], bH[4], aL[4], bL[4];
#pragma unroll
    for (int mi = 0; mi < 4; ++mi) {
      int r = (wm << 6) + (mi << 4) + l15;
      int off = r * 64 + ((kq ^ (r & 3)) << 4);
      aH[mi] = *(const bf16x8*)(L + off);
      if (SPLIT) aL[mi] = *(const bf16x8*)(L + 16384 + off);
    }
#pragma unroll
    for (int ni = 0; ni < 4; ++ni) {
      int c = (wn << 6) + (ni << 4) + l15;
      int off = c * 64 + ((kq ^ (c & 3)) << 4);
      bH[ni] = *(const bf16x8*)(L + 8192 + off);
      if (SPLIT) bL[ni] = *(const bf16x8*)(L + 24576 + off);
    }
#pragma unroll
    for (int mi = 0; mi < 4; ++mi)
#pragma unroll
      for (int ni = 0; ni < 4; ++ni) {
        acc[mi][ni] = __builtin_amdgcn_mfma_f32_16x16x32_bf16(aH[mi], bH[ni], acc[mi][ni], 0, 0, 0);
        if (SPLIT) {
          acc[mi][ni] = __builtin_amdgcn_mfma_f32_16x16x32_bf16(aL[mi], bH[ni], acc[mi][ni], 0, 0, 0);
          acc[mi][ni] = __builtin_amdgcn_mfma_f32_16x16x32_bf16(aH[mi], bL[ni], acc[mi][ni], 0, 0, 0);
        }
      }
  }
#pragma unroll
  for (int mi = 0; mi < 4; ++mi)
#pragma unroll
    for (int ni = 0; ni < 4; ++ni)
#pragma unroll
      for (int e = 0; e < 4; ++e) {
        int r = (wm << 6) + (mi << 4) + (kq << 2) + e;
        int c = (wn << 6) + (ni << 4) + l15;
        int gm = m0 + r, gn = n0 + c;
        float v = acc[mi][ni][e];
        if (OMODE == 0) {
          C[(long)gm * Crow + gn] = v;
        } else {
          v += bias[gn];
          C[((long)(gm & 63) * T_ + (gm >> 6)) * V_ + gn] = v;
        }
      }
}

// ---------------- 64x64 split-bf16 GEMM tile (device fn) ----------------
__device__ __forceinline__ void gemm64_tile(const u16* __restrict__ Ah,
                                            const u16* __restrict__ Al, int Ar,
                                            const u16* __restrict__ Bh,
                                            const u16* __restrict__ Bl, int Br,
                                            int kiters, char* L, f32x4 (&acc)[2][2]) {
  const int tid = threadIdx.x;
  const int lane = tid & 63, wid = tid >> 6;
  const int wm = wid & 1, wn = wid >> 1;
  const int l15 = lane & 15, kq = lane >> 4;
  for (int kt = 0; kt < kiters; ++kt) {
    __syncthreads();
    {
      int r = tid >> 2, slot = tid & 3;
      int so = ((slot ^ (r & 3)) << 4);
      long ga = (long)r * Ar + (kt << 5) + (slot << 3);
      long gb = (long)r * Br + (kt << 5) + (slot << 3);
      *(u32x4*)(L + r * 64 + so) = *(const u32x4*)(Ah + ga);
      *(u32x4*)(L + 4096 + r * 64 + so) = *(const u32x4*)(Bh + gb);
      *(u32x4*)(L + 8192 + r * 64 + so) = *(const u32x4*)(Al + ga);
      *(u32x4*)(L + 12288 + r * 64 + so) = *(const u32x4*)(Bl + gb);
    }
    __syncthreads();
    bf16x8 aH[2], aL[2], bH[2], bL[2];
#pragma unroll
    for (int mi = 0; mi < 2; ++mi) {
      int r = (wm << 5) + (mi << 4) + l15;
      int off = r * 64 + ((kq ^ (r & 3)) << 4);
      aH[mi] = *(const bf16x8*)(L + off);
      aL[mi] = *(const bf16x8*)(L + 8192 + off);
    }
#pragma unroll
    for (int ni = 0; ni < 2; ++ni) {
      int c = (wn << 5) + (ni << 4) + l15;
      int off = c * 64 + ((kq ^ (c & 3)) << 4);
      bH[ni] = *(const bf16x8*)(L + 4096 + off);
      bL[ni] = *(const bf16x8*)(L + 12288 + off);
    }
#pragma unroll
    for (int mi = 0; mi < 2; ++mi)
#pragma unroll
      for (int ni = 0; ni < 2; ++ni) {
        acc[mi][ni] = __builtin_amdgcn_mfma_f32_16x16x32_bf16(aH[mi], bH[ni], acc[mi][ni], 0, 0, 0);
        acc[mi][ni] = __builtin_amdgcn_mfma_f32_16x16x32_bf16(aL[mi], bH[ni], acc[mi][ni], 0, 0, 0);
        acc[mi][ni] = __builtin_amdgcn_mfma_f32_16x16x32_bf16(aH[mi], bL[ni], acc[mi][ni], 0, 0, 0);
      }
  }
}

// ---------------- grid barrier (all NB_ blocks resident) ----------------
__device__ __forceinline__ void gridbar(unsigned* flags, unsigned* gen, unsigned seq) {
  __syncthreads();
  if (threadIdx.x == 0) {
    __builtin_amdgcn_fence(__ATOMIC_RELEASE, "agent");
    __hip_atomic_store(flags + blockIdx.x * 16, seq, __ATOMIC_RELAXED,
                       __HIP_MEMORY_SCOPE_AGENT);
  }
  if (blockIdx.x == 0 && threadIdx.x < 64) {
    int l = threadIdx.x;
    for (;;) {
      unsigned a = __hip_atomic_load(flags + l * 16, __ATOMIC_RELAXED, __HIP_MEMORY_SCOPE_AGENT);
      unsigned b = __hip_atomic_load(flags + (l + 64) * 16, __ATOMIC_RELAXED, __HIP_MEMORY_SCOPE_AGENT);
      unsigned c = __hip_atomic_load(flags + (l + 128) * 16, __ATOMIC_RELAXED, __HIP_MEMORY_SCOPE_AGENT);
      if (__all(a >= seq && b >= seq && c >= seq)) break;
      __builtin_amdgcn_s_sleep(1);
    }
    if (l == 0)
      __hip_atomic_store(gen, seq, __ATOMIC_RELAXED, __HIP_MEMORY_SCOPE_AGENT);
  }
  if (threadIdx.x == 0) {
    while (__hip_atomic_load(gen, __ATOMIC_RELAXED, __HIP_MEMORY_SCOPE_AGENT) < seq)
      __builtin_amdgcn_s_sleep(1);
    __builtin_amdgcn_fence(__ATOMIC_ACQUIRE, "agent");
  }
  __syncthreads();
}

// ---------------- persistent recurrence kernel ----------------
__launch_bounds__(256)
__global__ void k_rec(const float* __restrict__ embi,
                      u16* __restrict__ dctx_h, u16* __restrict__ dctx_l,
                      u16* __restrict__ hh, u16* __restrict__ hl, float* __restrict__ hf,
                      const u16* __restrict__ wih_h, const u16* __restrict__ wih_l,
                      const u16* __restrict__ whh_h, const u16* __restrict__ whh_l,
                      const u16* __restrict__ l2_h, const u16* __restrict__ l2_l,
                      u16* __restrict__ cat_h, u16* __restrict__ cat_l,
                      float* __restrict__ gip, float* __restrict__ ghp,
                      const float* __restrict__ encT, const float* __restrict__ enc,
                      const int* __restrict__ xs_len,
                      const float* __restrict__ bih, const float* __restrict__ bhh,
                      float* __restrict__ dout, unsigned* flags, unsigned* gen) {
  __shared__ __attribute__((aligned(16))) char L[16384];
  const int bx = blockIdx.x;
  const int tid = threadIdx.x;
  const int lane = tid & 63, wid = tid >> 6;
  const int wm = wid & 1, wn = wid >> 1;
  const int l15 = lane & 15, kq = lane >> 4;
  const f32x4 z4 = {0.f, 0.f, 0.f, 0.f};
  unsigned seq = 1;

  for (int t = 0; t < T_; ++t) {
    // ---- P1: gates partial GEMMs (192 jobs) ----
    {
      const u16 *Ah, *Al, *Bh, *Bl;
      float* outp;
      int Ar, Br;
      if (bx < 96) {
        int nt = bx % 48, kc = bx / 48;
        Ah = dctx_h + (long)t * 65536 + kc * 512;
        Al = dctx_l + (long)t * 65536 + kc * 512;
        Ar = 1024;
        Bh = wih_h + 1024 + (long)nt * 64 * 2048 + kc * 512;
        Bl = wih_l + 1024 + (long)nt * 64 * 2048 + kc * 512;
        Br = 2048;
        outp = gip + (long)kc * 196608 + nt * 64;
      } else {
        int j2 = bx - 96;
        int nt = j2 % 48, kc = j2 / 48;
        Ah = hh + kc * 512;
        Al = hl + kc * 512;
        Ar = 1024;
        Bh = whh_h + (long)nt * 64 * 1024 + kc * 512;
        Bl = whh_l + (long)nt * 64 * 1024 + kc * 512;
        Br = 1024;
        outp = ghp + (long)kc * 196608 + nt * 64;
      }
      f32x4 acc[2][2];
#pragma unroll
      for (int i = 0; i < 2; ++i)
#pragma unroll
        for (int j = 0; j < 2; ++j) acc[i][j] = z4;
      gemm64_tile(Ah, Al, 1024, Bh, Bl, Br, 16, L, acc);
      (void)Ar;
#pragma unroll
      for (int mi = 0; mi < 2; ++mi)
#pragma unroll
        for (int ni = 0; ni < 2; ++ni)
#pragma unroll
          for (int e = 0; e < 4; ++e) {
            int r = (wm << 5) + (mi << 4) + (kq << 2) + e;
            int c = (wn << 5) + (ni << 4) + l15;
            outp[(long)r * 3072 + c] = acc[mi][ni][e];
          }
    }
    gridbar(flags, gen, seq++);

    // ---- P2: GRU finalize + attention (64 blocks) ----
    if (bx < 64) {
      int b = bx;
      float* hs = (float*)L;
      float* sc_s = (float*)(L + 4096);
      float* at_s = (float*)(L + 4352);
      const float* ebase = embi + ((long)t * 64 + b) * 3072;
      for (int j = tid; j < 1024; j += 256) {
        float ir = ebase[j] + gip[b * 3072 + j] + gip[196608 + b * 3072 + j] + bih[j];
        float iz = ebase[1024 + j] + gip[b * 3072 + 1024 + j] + gip[196608 + b * 3072 + 1024 + j] + bih[1024 + j];
        float in2 = ebase[2048 + j] + gip[b * 3072 + 2048 + j] + gip[196608 + b * 3072 + 2048 + j] + bih[2048 + j];
        float hr = ghp[b * 3072 + j] + ghp[196608 + b * 3072 + j] + bhh[j];
        float hz = ghp[b * 3072 + 1024 + j] + ghp[196608 + b * 3072 + 1024 + j] + bhh[1024 + j];
        float hn = ghp[b * 3072 + 2048 + j] + ghp[196608 + b * 3072 + 2048 + j] + bhh[2048 + j];
        float r = 1.f / (1.f + expf(-(ir + hr)));
        float z = 1.f / (1.f + expf(-(iz + hz)));
        float n = tanhf(in2 + r * hn);
        float hp = hf[b * 1024 + j];
        float h = (1.f - z) * n + z * hp;
        hs[j] = h;
        hf[b * 1024 + j] = h;
        split2(h, &hh[b * 1024 + j], &hl[b * 1024 + j]);
      }
      __syncthreads();
      {
        int s = tid >> 2, part = tid & 3;
        const float4* er = (const float4*)(encT + ((long)b * 64 + s) * 1024);
        const float4* hv = (const float4*)hs;
        float dot = 0.f;
        for (int q = part; q < 256; q += 4) {
          float4 e = er[q], h4 = hv[q];
          dot += e.x * h4.x + e.y * h4.y + e.z * h4.z + e.w * h4.w;
        }
        dot += __shfl_xor(dot, 1);
        dot += __shfl_xor(dot, 2);
        if (part == 0) sc_s[s] = dot;
      }
      __syncthreads();
      if (tid < 64) {
        int len = xs_len[b];
        float v = sc_s[tid];
        if (tid >= len || v == 0.0f) v = -1e10f;
        float m = v;
#pragma unroll
        for (int off = 32; off; off >>= 1) m = fmaxf(m, __shfl_xor(m, off));
        float p = expf(v - m);
        float sum = p;
#pragma unroll
        for (int off = 32; off; off >>= 1) sum += __shfl_xor(sum, off);
        float a = p / sum;
        at_s[tid] = a;
        dout[ATT_OFF + ((long)b * T_ + t) * S_ + tid] = a;
      }
      __syncthreads();
      {
        const float4* encb = (const float4*)(enc + (long)b * 64 * 1024);
        float c0 = 0.f, c1 = 0.f, c2 = 0.f, c3 = 0.f;
        for (int s2 = 0; s2 < 64; ++s2) {
          float a = at_s[s2];
          float4 e4 = encb[s2 * 256 + tid];
          c0 += a * e4.x; c1 += a * e4.y; c2 += a * e4.z; c3 += a * e4.w;
        }
        int k0 = tid * 4;
        float cv[4] = {c0, c1, c2, c3};
#pragma unroll
        for (int ii = 0; ii < 4; ++ii) {
          split2(cv[ii], &cat_h[b * 2048 + k0 + ii], &cat_l[b * 2048 + k0 + ii]);
          float h = hs[k0 + ii];
          split2(h, &cat_h[b * 2048 + 1024 + k0 + ii], &cat_l[b * 2048 + 1024 + k0 + ii]);
          if (t == T_ - 1) dout[HID_OFF + (long)b * 1024 + k0 + ii] = h;
        }
      }
    }
    gridbar(flags, gen, seq++);

    // ---- P3: ctx_new = tanh(cat @ l2^T) (16 blocks, full K) ----
    if (bx < 16) {
      f32x4 acc[2][2];
#pragma unroll
      for (int i = 0; i < 2; ++i)
#pragma unroll
        for (int j = 0; j < 2; ++j) acc[i][j] = z4;
      gemm64_tile(cat_h, cat_l, 2048, l2_h + (long)bx * 64 * 2048,
                  l2_l + (long)bx * 64 * 2048, 2048, 64, L, acc);
#pragma unroll
      for (int mi = 0; mi < 2; ++mi)
#pragma unroll
        for (int ni = 0; ni < 2; ++ni)
#pragma unroll
          for (int e = 0; e < 4; ++e) {
            int b = (wm << 5) + (mi << 4) + (kq << 2) + e;
            int c = (wn << 5) + (ni << 4) + l15;
            int gcol = bx * 64 + c;
            float v = tanhf(acc[mi][ni][e]);
            long o = (long)(t + 1) * 65536 + (long)b * 1024 + gcol;
            split2(v, &dctx_h[o], &dctx_l[o]);
            if (t == T_ - 1) dout[CTF_OFF + (long)b * 1024 + gcol] = v;
          }
    }
    gridbar(flags, gen, seq++);
  }
}

// ---------------- in-place log-softmax over V per row ----------------
__device__ __forceinline__ void lse_comb(float& m, float& s, float mo, float so) {
  float M = fmaxf(m, mo);
  s = s * __expf(m - M) + so * __expf(mo - M);
  m = M;
}

__launch_bounds__(256)
__global__ void k_lsm(float* __restrict__ dout) {
  long base = (long)blockIdx.x * V_;
  int tid = threadIdx.x;
  float m = -3.0e38f, s = 0.f;
  for (int v = tid; v < V_; v += 256) {
    float x = dout[base + v];
    if (x > m) {
      s = s * __expf(m - x) + 1.f;
      m = x;
    } else {
      s += __expf(x - m);
    }
  }
#pragma unroll
  for (int off = 32; off; off >>= 1) {
    float mo = __shfl_xor(m, off), so = __shfl_xor(s, off);
    lse_comb(m, s, mo, so);
  }
  __shared__ float ms[4], ss[4];
  if ((tid & 63) == 0) { ms[tid >> 6] = m; ss[tid >> 6] = s; }
  __syncthreads();
  float M = ms[0], S = ss[0];
  for (int w2 = 1; w2 < 4; ++w2) lse_comb(M, S, ms[w2], ss[w2]);
  float logden = M + logf(S);
  for (int v = tid; v < V_; v += 256) dout[base + v] -= logden;
}

// ---------------- host launcher ----------------
extern "C" void kernel_launch(void* const* d_in, const int* in_sizes, int n_in,
                              void* d_out, int out_size, void* d_ws, size_t ws_size,
                              hipStream_t stream) {
  (void)in_sizes; (void)n_in; (void)out_size;
  const int* input = (const int*)d_in[0];
  const float* memory = (const float*)d_in[1];
  const float* enc = (const float*)d_in[2];
  const int* xs_len = (const int*)d_in[3];
  const float* emb = (const float*)d_in[4];
  const float* wih = (const float*)d_in[5];
  const float* whh = (const float*)d_in[6];
  const float* bih = (const float*)d_in[7];
  const float* bhh = (const float*)d_in[8];
  const float* l1 = (const float*)d_in[9];
  const float* l2 = (const float*)d_in[10];
  const float* wout = (const float*)d_in[11];
  const float* bout = (const float*)d_in[12];
  float* out = (float*)d_out;
  char* w = (char*)d_ws;

  size_t off = 0;
  auto alloc = [&](size_t bytes) {
    size_t o = off;
    off = (off + bytes + 255) & ~(size_t)255;
    return o;
  };
  const size_t N_WIH = 3072UL * 2048, N_WHH = 3072UL * 1024, N_L2 = 1024UL * 2048;
  const size_t N_L1 = 1024UL * 1024, N_ENC = 4096UL * 1024, N_WOUT = 32000UL * 1024;
  const size_t N_EMBX = 2048UL * 1024, N_ENCT = 4096UL * 1024, N_CTX = 33UL * 65536;
  const size_t N_EMBI = 2048UL * 3072;

  size_t o_wih_h = alloc(2 * N_WIH), o_wih_l = alloc(2 * N_WIH);
  size_t o_whh_h = alloc(2 * N_WHH), o_whh_l = alloc(2 * N_WHH);
  size_t o_l2_h = alloc(2 * N_L2), o_l2_l = alloc(2 * N_L2);
  size_t o_l1t_h = alloc(2 * N_L1), o_l1t_l = alloc(2 * N_L1);
  size_t o_enc_h = alloc(2 * N_ENC), o_enc_l = alloc(2 * N_ENC);
  size_t o_wout = alloc(2 * N_WOUT);
  size_t o_embx_h = alloc(2 * N_EMBX), o_embx_l = alloc(2 * N_EMBX);
  size_t o_encT = alloc(4 * N_ENCT);
  size_t o_embi = alloc(4 * N_EMBI);
  size_t o_ctx_h = alloc(2 * N_CTX), o_ctx_l = alloc(2 * N_CTX);
  size_t o_hf = alloc(4 * 65536), o_hh = alloc(2 * 65536), o_hl = alloc(2 * 65536);
  size_t o_cat_h = alloc(2 * 131072), o_cat_l = alloc(2 * 131072);
  size_t o_gip = alloc(4 * 2 * 196608), o_ghp = alloc(4 * 2 * 196608);
  size_t o_bar = alloc(16384);

  if (off > ws_size) {
    k_guard<<<1, 1, 0, stream>>>(out, 1.0e8f + (float)(ws_size >> 20));
    return;
  }

  u16* wih_h = (u16*)(w + o_wih_h);   u16* wih_l = (u16*)(w + o_wih_l);
  u16* whh_h = (u16*)(w + o_whh_h);   u16* whh_l = (u16*)(w + o_whh_l);
  u16* l2_h = (u16*)(w + o_l2_h);     u16* l2_l = (u16*)(w + o_l2_l);
  u16* l1t_h = (u16*)(w + o_l1t_h);   u16* l1t_l = (u16*)(w + o_l1t_l);
  u16* enc_h = (u16*)(w + o_enc_h);   u16* enc_l = (u16*)(w + o_enc_l);
  u16* wout_b = (u16*)(w + o_wout);
  u16* embx_h = (u16*)(w + o_embx_h); u16* embx_l = (u16*)(w + o_embx_l);
  float* encT = (float*)(w + o_encT);
  float* embi = (float*)(w + o_embi);
  u16* ctx_h = (u16*)(w + o_ctx_h);   u16* ctx_l = (u16*)(w + o_ctx_l);
  float* hf = (float*)(w + o_hf);
  u16* hh = (u16*)(w + o_hh);         u16* hl = (u16*)(w + o_hl);
  u16* cat_h = (u16*)(w + o_cat_h);   u16* cat_l = (u16*)(w + o_cat_l);
  float* gip = (float*)(w + o_gip);
  float* ghp = (float*)(w + o_ghp);
  unsigned* flags = (unsigned*)(w + o_bar);
  unsigned* gen = flags + 3072;

  // prep
  k_split<<<2048, 256, 0, stream>>>(wih, wih_h, wih_l, (int)N_WIH);
  k_split<<<2048, 256, 0, stream>>>(whh, whh_h, whh_l, (int)N_WHH);
  k_split<<<2048, 256, 0, stream>>>(l2, l2_h, l2_l, (int)N_L2);
  k_split<<<2048, 256, 0, stream>>>(enc, enc_h, enc_l, (int)N_ENC);
  k_l1t<<<256, 256, 0, stream>>>(l1, l1t_h, l1t_l);
  k_tobf<<<4096, 256, 0, stream>>>(wout, wout_b, (int)N_WOUT);
  k_embx<<<2048, 256, 0, stream>>>(input, emb, embx_h, embx_l);
  k_h0<<<256, 256, 0, stream>>>(memory, hf, hh, hl);
  hipMemsetAsync(ctx_h, 0, 131072, stream);  // dctx slot 0 = zeros
  hipMemsetAsync(ctx_l, 0, 131072, stream);
  hipMemsetAsync(flags, 0, 16384, stream);   // barrier state (reset every launch)

  // encT = enc @ l1  (split-bf16)
  k_gemm128<1, 0><<<256, 256, 0, stream>>>(enc_h, enc_l, l1t_h, l1t_l, encT, nullptr,
                                           32, 8, 1024, 1024, 1024, 1024);
  // embi = embx @ w_ih[:, :1024]^T  (split-bf16): M=2048, N=3072, K=1024
  k_gemm128<1, 0><<<384, 256, 0, stream>>>(embx_h, embx_l, wih_h, wih_l, embi, nullptr,
                                           16, 24, 1024, 1024, 2048, 3072);

  // persistent recurrence
  k_rec<<<NB_, 256, 0, stream>>>(embi, ctx_h, ctx_l, hh, hl, hf,
                                 wih_h, wih_l, whh_h, whh_l, l2_h, l2_l,
                                 cat_h, cat_l, gip, ghp, encT, enc, xs_len,
                                 bih, bhh, out, flags, gen);

  // logits = dctx_all @ w_out^T + b_out, scattered to [b][t][v]
  k_gemm128<0, 1><<<4000, 256, 0, stream>>>(ctx_h + 65536, nullptr, wout_b, nullptr,
                                            out, bout, 16, 250, 1024, 1024, 1024, 0);
  // in-place log-softmax per (b,t) row
  k_lsm<<<2048, 256, 0, stream>>>(out);
}

// Round 3
// 2890.652 us; speedup vs baseline: 1.2600x; 1.2600x over previous
//
#include <hip/hip_runtime.h>

// ---------------------------------------------------------------------------
// AttentionDecoder: B=64 T=32 S=64 H=1024 V=32000
// R3: persistent recurrence WITHOUT cache-invalidating fences.
//  - All inter-block data (gip/ghp, cat, hh/hl, dctx, ctxp) moves through
//    agent-scope RELAXED atomics (coherent path, bypasses non-coherent L2).
//  - Weights/encT/embi use normal cached loads; never invalidated -> L2-warm
//    across all 32 steps (R2's fence invalidated L2 every phase -> 1.28 GB
//    HBM refetch; that was the 3 ms).
//  - Barrier: release flag store + distributed relaxed polling (no acquire
//    fence; post-barrier reads are themselves coherent-path atomics).
//  - 4 phases/step: gates(192) | GRU+attn(64) | l2-splitK(64) | ctxfin(64)
//  - Logits GEMM + log-softmax unchanged from R1.
// ---------------------------------------------------------------------------

#define B_ 64
#define T_ 32
#define S_ 64
#define H_ 1024
#define V_ 32000
#define NB_ 192

#define HID_OFF 65536000L
#define ATT_OFF 65601536L
#define CTF_OFF 65732608L

typedef __attribute__((ext_vector_type(8))) short bf16x8;
typedef __attribute__((ext_vector_type(4))) float f32x4;
typedef __attribute__((ext_vector_type(4))) unsigned int u32x4;
typedef unsigned short u16;
typedef unsigned long long u64;

__device__ __forceinline__ u16 f2bf(float v) {
  unsigned int u = __float_as_uint(v);
  unsigned int r = (u + 0x7fffu + ((u >> 16) & 1u)) >> 16;  // RNE
  return (u16)r;
}
__device__ __forceinline__ float bf2f(u16 h) {
  return __uint_as_float(((unsigned int)h) << 16);
}
__device__ __forceinline__ void split2(float v, u16* hi, u16* lo) {
  u16 h = f2bf(v);
  *hi = h;
  *lo = f2bf(v - bf2f(h));
}

// ---- coherent-path (agent-scope relaxed atomic) access helpers ----
__device__ __forceinline__ u64 aload_u64(const void* p) {
  return __hip_atomic_load((const u64*)p, __ATOMIC_RELAXED, __HIP_MEMORY_SCOPE_AGENT);
}
__device__ __forceinline__ void astore_u64(void* p, u64 v) {
  __hip_atomic_store((u64*)p, v, __ATOMIC_RELAXED, __HIP_MEMORY_SCOPE_AGENT);
}
__device__ __forceinline__ void astore_f32(float* p, float v) {
  __hip_atomic_store((unsigned*)p, __float_as_uint(v), __ATOMIC_RELAXED,
                     __HIP_MEMORY_SCOPE_AGENT);
}
__device__ __forceinline__ void aload4f(const float* p, float* d) {
  u64 a = aload_u64(p), b = aload_u64(p + 2);
  d[0] = __uint_as_float((unsigned)a);
  d[1] = __uint_as_float((unsigned)(a >> 32));
  d[2] = __uint_as_float((unsigned)b);
  d[3] = __uint_as_float((unsigned)(b >> 32));
}
__device__ __forceinline__ u32x4 ld16(const u16* p) { return *(const u32x4*)p; }
__device__ __forceinline__ u32x4 ld16c(const u16* p) {
  u64 a = aload_u64(p), b = aload_u64(p + 4);
  u32x4 r;
  r[0] = (unsigned)a; r[1] = (unsigned)(a >> 32);
  r[2] = (unsigned)b; r[3] = (unsigned)(b >> 32);
  return r;
}

// ---------------- conversion / prep kernels ----------------

__global__ void k_split(const float* __restrict__ src, u16* __restrict__ hi,
                        u16* __restrict__ lo, int n) {
  int i = blockIdx.x * blockDim.x + threadIdx.x;
  int stride = gridDim.x * blockDim.x;
  for (; i < n; i += stride) split2(src[i], &hi[i], &lo[i]);
}

__global__ void k_tobf(const float* __restrict__ src, u16* __restrict__ dst, int n) {
  int i = blockIdx.x * blockDim.x + threadIdx.x;
  int stride = gridDim.x * blockDim.x;
  for (; i < n; i += stride) dst[i] = f2bf(src[i]);
}

// l1 (H,H) row-major [i][k] -> l1T hi/lo [k][i]
__global__ void k_l1t(const float* __restrict__ l1, u16* __restrict__ hi,
                      u16* __restrict__ lo) {
  __shared__ float tile[64][65];
  int it = blockIdx.x & 15, kt = blockIdx.x >> 4;
  for (int q = 0; q < 16; ++q) {
    int idx = q * 256 + threadIdx.x;
    int r = idx >> 6, c = idx & 63;
    tile[r][c] = l1[(long)(it * 64 + r) * H_ + kt * 64 + c];
  }
  __syncthreads();
  for (int q = 0; q < 16; ++q) {
    int idx = q * 256 + threadIdx.x;
    int r = idx >> 6, c = idx & 63;
    long o = (long)(kt * 64 + r) * H_ + it * 64 + c;
    split2(tile[c][r], &hi[o], &lo[o]);
  }
}

// gather embeddings: embx[t][b][k] hi/lo
__global__ void k_embx(const int* __restrict__ inp, const float* __restrict__ emb,
                       u16* __restrict__ hi, u16* __restrict__ lo) {
  int bt = blockIdx.x;
  int b = bt >> 5, t = bt & 31;
  int id = inp[b * T_ + t];
  const float* src = emb + (long)id * H_;
  long base = (long)(t * B_ + b) * H_;
  for (int k = threadIdx.x; k < H_; k += 256) split2(src[k], &hi[base + k], &lo[base + k]);
}

__global__ void k_h0(const float* __restrict__ mem, float* __restrict__ hf,
                     u16* __restrict__ hh, u16* __restrict__ hl) {
  int i = blockIdx.x * 256 + threadIdx.x;  // 65536
  float v = mem[i];
  hf[i] = v;
  split2(v, &hh[i], &hl[i]);
}

__global__ void k_guard(float* out, float v) {
  if (blockIdx.x == 0 && threadIdx.x == 0) out[0] = v;
}

// ---------------- 128x128 tile GEMM (BK=32), optional split-bf16 ----------------
template <int SPLIT, int OMODE>
__launch_bounds__(256)
__global__ void k_gemm128(const u16* __restrict__ Ah, const u16* __restrict__ Al,
                          const u16* __restrict__ Bh, const u16* __restrict__ Bl,
                          float* __restrict__ C, const float* __restrict__ bias,
                          int Mtiles, int Ntiles, int K, int Arow, int Brow, int Crow) {
  (void)Ntiles;
  int bx = blockIdx.x;
  int mt = bx % Mtiles, nt = bx / Mtiles;
  int m0 = mt * 128, n0 = nt * 128;

  __shared__ __attribute__((aligned(16))) u16 lds[(SPLIT ? 4 : 2) * 4096];
  char* L = (char*)lds;
  const int tid = threadIdx.x;
  const int lane = tid & 63, wid = tid >> 6;
  const int wm = wid & 1, wn = wid >> 1;
  const int l15 = lane & 15, kq = lane >> 4;

  f32x4 acc[4][4];
  const f32x4 z4 = {0.f, 0.f, 0.f, 0.f};
#pragma unroll
  for (int i = 0; i < 4; ++i)
#pragma unroll
    for (int j = 0; j < 4; ++j) acc[i][j] = z4;

  const int ksteps = K >> 5;
  for (int kt = 0; kt < ksteps; ++kt) {
    __syncthreads();
#pragma unroll
    for (int h2 = 0; h2 < 2; ++h2) {
      int r = (tid >> 2) + (h2 << 6);
      int slot = tid & 3;
      int so = ((slot ^ (r & 3)) << 4);
      long ga = (long)(m0 + r) * Arow + (kt << 5) + (slot << 3);
      long gb = (long)(n0 + r) * Brow + (kt << 5) + (slot << 3);
      *(u32x4*)(L + r * 64 + so) = *(const u32x4*)(Ah + ga);
      *(u32x4*)(L + 8192 + r * 64 + so) = *(const u32x4*)(Bh + gb);
      if (SPLIT) {
        *(u32x4*)(L + 16384 + r * 64 + so) = *(const u32x4*)(Al + ga);
        *(u32x4*)(L + 24576 + r * 64 + so) = *(const u32x4*)(Bl + gb);
      }
    }
    __syncthreads();
    bf16x8 aH[4], bH[4], aL[4], bL[4];
#pragma unroll
    for (int mi = 0; mi < 4; ++mi) {
      int r = (wm << 6) + (mi << 4) + l15;
      int off = r * 64 + ((kq ^ (r & 3)) << 4);
      aH[mi] = *(const bf16x8*)(L + off);
      if (SPLIT) aL[mi] = *(const bf16x8*)(L + 16384 + off);
    }
#pragma unroll
    for (int ni = 0; ni < 4; ++ni) {
      int c = (wn << 6) + (ni << 4) + l15;
      int off = c * 64 + ((kq ^ (c & 3)) << 4);
      bH[ni] = *(const bf16x8*)(L + 8192 + off);
      if (SPLIT) bL[ni] = *(const bf16x8*)(L + 24576 + off);
    }
#pragma unroll
    for (int mi = 0; mi < 4; ++mi)
#pragma unroll
      for (int ni = 0; ni < 4; ++ni) {
        acc[mi][ni] = __builtin_amdgcn_mfma_f32_16x16x32_bf16(aH[mi], bH[ni], acc[mi][ni], 0, 0, 0);
        if (SPLIT) {
          acc[mi][ni] = __builtin_amdgcn_mfma_f32_16x16x32_bf16(aL[mi], bH[ni], acc[mi][ni], 0, 0, 0);
          acc[mi][ni] = __builtin_amdgcn_mfma_f32_16x16x32_bf16(aH[mi], bL[ni], acc[mi][ni], 0, 0, 0);
        }
      }
  }
#pragma unroll
  for (int mi = 0; mi < 4; ++mi)
#pragma unroll
    for (int ni = 0; ni < 4; ++ni)
#pragma unroll
      for (int e = 0; e < 4; ++e) {
        int r = (wm << 6) + (mi << 4) + (kq << 2) + e;
        int c = (wn << 6) + (ni << 4) + l15;
        int gm = m0 + r, gn = n0 + c;
        float v = acc[mi][ni][e];
        if (OMODE == 0) {
          C[(long)gm * Crow + gn] = v;
        } else {
          v += bias[gn];
          C[((long)(gm & 63) * T_ + (gm >> 6)) * V_ + gn] = v;
        }
      }
}

// ---------------- 64x64 split-bf16 GEMM tile (device fn) ----------------
// COHA: load A (hi/lo) via coherent-path atomics. Reg double-buffered.
template <int COHA>
__device__ __forceinline__ void gemm64_tile(const u16* __restrict__ Ah,
                                            const u16* __restrict__ Al, int Ar,
                                            const u16* __restrict__ Bh,
                                            const u16* __restrict__ Bl, int Br,
                                            int kiters, char* L, f32x4 (&acc)[2][2]) {
  const int tid = threadIdx.x;
  const int lane = tid & 63, wid = tid >> 6;
  const int wm = wid & 1, wn = wid >> 1;
  const int l15 = lane & 15, kq = lane >> 4;
  const int r = tid >> 2, slot = tid & 3;
  const int so = ((slot ^ (r & 3)) << 4);

  u32x4 rAh, rBh, rAl, rBl;
  {
    long ga = (long)r * Ar + (slot << 3);
    long gb = (long)r * Br + (slot << 3);
    rAh = COHA ? ld16c(Ah + ga) : ld16(Ah + ga);
    rAl = COHA ? ld16c(Al + ga) : ld16(Al + ga);
    rBh = ld16(Bh + gb);
    rBl = ld16(Bl + gb);
  }
  for (int kt = 0; kt < kiters; ++kt) {
    __syncthreads();
    *(u32x4*)(L + r * 64 + so) = rAh;
    *(u32x4*)(L + 4096 + r * 64 + so) = rBh;
    *(u32x4*)(L + 8192 + r * 64 + so) = rAl;
    *(u32x4*)(L + 12288 + r * 64 + so) = rBl;
    __syncthreads();
    if (kt + 1 < kiters) {
      long ga = (long)r * Ar + ((kt + 1) << 5) + (slot << 3);
      long gb = (long)r * Br + ((kt + 1) << 5) + (slot << 3);
      rAh = COHA ? ld16c(Ah + ga) : ld16(Ah + ga);
      rAl = COHA ? ld16c(Al + ga) : ld16(Al + ga);
      rBh = ld16(Bh + gb);
      rBl = ld16(Bl + gb);
    }
    bf16x8 aH[2], aL[2], bH[2], bL[2];
#pragma unroll
    for (int mi = 0; mi < 2; ++mi) {
      int rr = (wm << 5) + (mi << 4) + l15;
      int off = rr * 64 + ((kq ^ (rr & 3)) << 4);
      aH[mi] = *(const bf16x8*)(L + off);
      aL[mi] = *(const bf16x8*)(L + 8192 + off);
    }
#pragma unroll
    for (int ni = 0; ni < 2; ++ni) {
      int c = (wn << 5) + (ni << 4) + l15;
      int off = c * 64 + ((kq ^ (c & 3)) << 4);
      bH[ni] = *(const bf16x8*)(L + 4096 + off);
      bL[ni] = *(const bf16x8*)(L + 12288 + off);
    }
#pragma unroll
    for (int mi = 0; mi < 2; ++mi)
#pragma unroll
      for (int ni = 0; ni < 2; ++ni) {
        acc[mi][ni] = __builtin_amdgcn_mfma_f32_16x16x32_bf16(aH[mi], bH[ni], acc[mi][ni], 0, 0, 0);
        acc[mi][ni] = __builtin_amdgcn_mfma_f32_16x16x32_bf16(aL[mi], bH[ni], acc[mi][ni], 0, 0, 0);
        acc[mi][ni] = __builtin_amdgcn_mfma_f32_16x16x32_bf16(aH[mi], bL[ni], acc[mi][ni], 0, 0, 0);
      }
  }
}

// ---------------- grid barrier: release flag + distributed relaxed poll ----
__device__ __forceinline__ void gridbar(unsigned* flags, unsigned seq) {
  __syncthreads();
  if (threadIdx.x == 0)
    __hip_atomic_store(flags + blockIdx.x * 16, seq, __ATOMIC_RELEASE,
                       __HIP_MEMORY_SCOPE_AGENT);
  if (threadIdx.x < 64) {
    int l = threadIdx.x;
    for (;;) {
      unsigned a = __hip_atomic_load(flags + l * 16, __ATOMIC_RELAXED, __HIP_MEMORY_SCOPE_AGENT);
      unsigned b = __hip_atomic_load(flags + (l + 64) * 16, __ATOMIC_RELAXED, __HIP_MEMORY_SCOPE_AGENT);
      unsigned c = __hip_atomic_load(flags + (l + 128) * 16, __ATOMIC_RELAXED, __HIP_MEMORY_SCOPE_AGENT);
      if (__all((a >= seq) & (b >= seq) & (c >= seq))) break;
      __builtin_amdgcn_s_sleep(1);
    }
  }
  __syncthreads();
}

// ---------------- persistent recurrence kernel ----------------
__launch_bounds__(256)
__global__ void k_rec(const float* __restrict__ embi,
                      u16* __restrict__ dctx_h, u16* __restrict__ dctx_l,
                      u16* __restrict__ hh, u16* __restrict__ hl, float* __restrict__ hf,
                      const u16* __restrict__ wih_h, const u16* __restrict__ wih_l,
                      const u16* __restrict__ whh_h, const u16* __restrict__ whh_l,
                      const u16* __restrict__ l2_h, const u16* __restrict__ l2_l,
                      u16* __restrict__ cat_h, u16* __restrict__ cat_l,
                      float* __restrict__ gip, float* __restrict__ ghp,
                      float* __restrict__ ctxp,
                      const float* __restrict__ encT, const float* __restrict__ enc,
                      const int* __restrict__ xs_len,
                      const float* __restrict__ bih, const float* __restrict__ bhh,
                      float* __restrict__ dout, unsigned* flags) {
  __shared__ __attribute__((aligned(16))) char L[16384];
  const int bx = blockIdx.x;
  const int tid = threadIdx.x;
  const int lane = tid & 63, wid = tid >> 6;
  const int wm = wid & 1, wn = wid >> 1;
  const int l15 = lane & 15, kq = lane >> 4;
  const f32x4 z4 = {0.f, 0.f, 0.f, 0.f};
  unsigned seq = 1;

  for (int t = 0; t < T_; ++t) {
    // ---- Ph1: gates partial GEMMs (192 blocks) ----
    {
      const u16 *Ah, *Al, *Bh, *Bl;
      float* outp;
      int Br;
      if (bx < 96) {
        int nt = bx % 48, kc = bx / 48;
        Ah = dctx_h + (long)t * 65536 + kc * 512;
        Al = dctx_l + (long)t * 65536 + kc * 512;
        Bh = wih_h + 1024 + (long)nt * 64 * 2048 + kc * 512;
        Bl = wih_l + 1024 + (long)nt * 64 * 2048 + kc * 512;
        Br = 2048;
        outp = gip + (long)kc * 196608 + nt * 64;
      } else {
        int j2 = bx - 96;
        int nt = j2 % 48, kc = j2 / 48;
        Ah = hh + kc * 512;
        Al = hl + kc * 512;
        Bh = whh_h + (long)nt * 64 * 1024 + kc * 512;
        Bl = whh_l + (long)nt * 64 * 1024 + kc * 512;
        Br = 1024;
        outp = ghp + (long)kc * 196608 + nt * 64;
      }
      f32x4 acc[2][2];
#pragma unroll
      for (int i = 0; i < 2; ++i)
#pragma unroll
        for (int j = 0; j < 2; ++j) acc[i][j] = z4;
      gemm64_tile<1>(Ah, Al, 1024, Bh, Bl, Br, 16, L, acc);
#pragma unroll
      for (int mi = 0; mi < 2; ++mi)
#pragma unroll
        for (int ni = 0; ni < 2; ++ni)
#pragma unroll
          for (int e = 0; e < 4; ++e) {
            int r = (wm << 5) + (mi << 4) + (kq << 2) + e;
            int c = (wn << 5) + (ni << 4) + l15;
            astore_f32(outp + (long)r * 3072 + c, acc[mi][ni][e]);
          }
    }
    gridbar(flags, seq++);

    // ---- Ph2: GRU finalize + attention (64 blocks) ----
    if (bx < 64) {
      int b = bx;
      float* hs = (float*)L;
      float* sc_s = (float*)(L + 4096);
      float* at_s = (float*)(L + 4352);
      const float* ebase = embi + ((long)t * 64 + b) * 3072;
      {
        int j0 = tid * 4;
        float g0[4], g1[4], q0[4], q1[4];
        float hv4[4];
        u64 ph = 0, pl = 0;
        aload4f(gip + b * 3072 + j0, g0);
        aload4f(gip + 196608 + b * 3072 + j0, g1);
        aload4f(ghp + b * 3072 + j0, q0);
        aload4f(ghp + 196608 + b * 3072 + j0, q1);
        float ir4[4], hr4[4];
#pragma unroll
        for (int ii = 0; ii < 4; ++ii) {
          ir4[ii] = ebase[j0 + ii] + g0[ii] + g1[ii] + bih[j0 + ii];
          hr4[ii] = q0[ii] + q1[ii] + bhh[j0 + ii];
        }
        aload4f(gip + b * 3072 + 1024 + j0, g0);
        aload4f(gip + 196608 + b * 3072 + 1024 + j0, g1);
        aload4f(ghp + b * 3072 + 1024 + j0, q0);
        aload4f(ghp + 196608 + b * 3072 + 1024 + j0, q1);
        float iz4[4], hz4[4];
#pragma unroll
        for (int ii = 0; ii < 4; ++ii) {
          iz4[ii] = ebase[1024 + j0 + ii] + g0[ii] + g1[ii] + bih[1024 + j0 + ii];
          hz4[ii] = q0[ii] + q1[ii] + bhh[1024 + j0 + ii];
        }
        aload4f(gip + b * 3072 + 2048 + j0, g0);
        aload4f(gip + 196608 + b * 3072 + 2048 + j0, g1);
        aload4f(ghp + b * 3072 + 2048 + j0, q0);
        aload4f(ghp + 196608 + b * 3072 + 2048 + j0, q1);
#pragma unroll
        for (int ii = 0; ii < 4; ++ii) {
          float in2 = ebase[2048 + j0 + ii] + g0[ii] + g1[ii] + bih[2048 + j0 + ii];
          float hn = q0[ii] + q1[ii] + bhh[2048 + j0 + ii];
          float r = 1.f / (1.f + expf(-(ir4[ii] + hr4[ii])));
          float z = 1.f / (1.f + expf(-(iz4[ii] + hz4[ii])));
          float n = tanhf(in2 + r * hn);
          float hp = hf[b * 1024 + j0 + ii];
          float h = (1.f - z) * n + z * hp;
          hv4[ii] = h;
          hs[j0 + ii] = h;
          hf[b * 1024 + j0 + ii] = h;
          u16 hi, lo;
          split2(h, &hi, &lo);
          ph |= (u64)hi << (16 * ii);
          pl |= (u64)lo << (16 * ii);
        }
        astore_u64(hh + b * 1024 + j0, ph);
        astore_u64(hl + b * 1024 + j0, pl);
        (void)hv4;
      }
      __syncthreads();
      {
        int s = tid >> 2, part = tid & 3;
        const float4* er = (const float4*)(encT + ((long)b * 64 + s) * 1024);
        const float4* hv = (const float4*)hs;
        float dot = 0.f;
        for (int q = part; q < 256; q += 4) {
          float4 e = er[q], h4 = hv[q];
          dot += e.x * h4.x + e.y * h4.y + e.z * h4.z + e.w * h4.w;
        }
        dot += __shfl_xor(dot, 1);
        dot += __shfl_xor(dot, 2);
        if (part == 0) sc_s[s] = dot;
      }
      __syncthreads();
      if (tid < 64) {
        int len = xs_len[b];
        float v = sc_s[tid];
        if (tid >= len || v == 0.0f) v = -1e10f;
        float m = v;
#pragma unroll
        for (int off = 32; off; off >>= 1) m = fmaxf(m, __shfl_xor(m, off));
        float p = expf(v - m);
        float sum = p;
#pragma unroll
        for (int off = 32; off; off >>= 1) sum += __shfl_xor(sum, off);
        float a = p / sum;
        at_s[tid] = a;
        dout[ATT_OFF + ((long)b * T_ + t) * S_ + tid] = a;
      }
      __syncthreads();
      {
        const float4* encb = (const float4*)(enc + (long)b * 64 * 1024);
        float c0 = 0.f, c1 = 0.f, c2 = 0.f, c3 = 0.f;
        for (int s2 = 0; s2 < 64; ++s2) {
          float a = at_s[s2];
          float4 e4 = encb[s2 * 256 + tid];
          c0 += a * e4.x; c1 += a * e4.y; c2 += a * e4.z; c3 += a * e4.w;
        }
        int k0 = tid * 4;
        float cv[4] = {c0, c1, c2, c3};
        u64 ch = 0, cl = 0, hh2 = 0, hl2 = 0;
#pragma unroll
        for (int ii = 0; ii < 4; ++ii) {
          u16 hi, lo;
          split2(cv[ii], &hi, &lo);
          ch |= (u64)hi << (16 * ii);
          cl |= (u64)lo << (16 * ii);
          float h = hs[k0 + ii];
          split2(h, &hi, &lo);
          hh2 |= (u64)hi << (16 * ii);
          hl2 |= (u64)lo << (16 * ii);
          if (t == T_ - 1) dout[HID_OFF + (long)b * 1024 + k0 + ii] = h;
        }
        astore_u64(cat_h + b * 2048 + k0, ch);
        astore_u64(cat_l + b * 2048 + k0, cl);
        astore_u64(cat_h + b * 2048 + 1024 + k0, hh2);
        astore_u64(cat_l + b * 2048 + 1024 + k0, hl2);
      }
    }
    gridbar(flags, seq++);

    // ---- Ph3: l2 split-K GEMM (64 blocks: 16 nt x 4 kc) ----
    if (bx < 64) {
      int nt = bx & 15, kc = bx >> 4;
      f32x4 acc[2][2];
#pragma unroll
      for (int i = 0; i < 2; ++i)
#pragma unroll
        for (int j = 0; j < 2; ++j) acc[i][j] = z4;
      gemm64_tile<1>(cat_h + kc * 512, cat_l + kc * 512, 2048,
                     l2_h + (long)nt * 64 * 2048 + kc * 512,
                     l2_l + (long)nt * 64 * 2048 + kc * 512, 2048, 16, L, acc);
      float* outp = ctxp + (long)kc * 65536 + nt * 64;
#pragma unroll
      for (int mi = 0; mi < 2; ++mi)
#pragma unroll
        for (int ni = 0; ni < 2; ++ni)
#pragma unroll
          for (int e = 0; e < 4; ++e) {
            int r = (wm << 5) + (mi << 4) + (kq << 2) + e;
            int c = (wn << 5) + (ni << 4) + l15;
            astore_f32(outp + (long)r * 1024 + c, acc[mi][ni][e]);
          }
    }
    gridbar(flags, seq++);

    // ---- Ph4: ctx finalize (64 blocks) ----
    if (bx < 64) {
      int base = bx * 1024 + tid * 4;
      float s0[4], s1[4], s2[4], s3[4];
      aload4f(ctxp + base, s0);
      aload4f(ctxp + 65536 + base, s1);
      aload4f(ctxp + 131072 + base, s2);
      aload4f(ctxp + 196608 + base, s3);
      u64 ph = 0, pl = 0;
#pragma unroll
      for (int ii = 0; ii < 4; ++ii) {
        float v = tanhf(s0[ii] + s1[ii] + s2[ii] + s3[ii]);
        u16 hi, lo;
        split2(v, &hi, &lo);
        ph |= (u64)hi << (16 * ii);
        pl |= (u64)lo << (16 * ii);
        if (t == T_ - 1) dout[CTF_OFF + base + ii] = v;
      }
      astore_u64(dctx_h + (long)(t + 1) * 65536 + base, ph);
      astore_u64(dctx_l + (long)(t + 1) * 65536 + base, pl);
    }
    gridbar(flags, seq++);
  }
}

// ---------------- in-place log-softmax over V per row ----------------
__device__ __forceinline__ void lse_comb(float& m, float& s, float mo, float so) {
  float M = fmaxf(m, mo);
  s = s * __expf(m - M) + so * __expf(mo - M);
  m = M;
}

__launch_bounds__(256)
__global__ void k_lsm(float* __restrict__ dout) {
  long base = (long)blockIdx.x * V_;
  int tid = threadIdx.x;
  float m = -3.0e38f, s = 0.f;
  for (int v = tid; v < V_; v += 256) {
    float x = dout[base + v];
    if (x > m) {
      s = s * __expf(m - x) + 1.f;
      m = x;
    } else {
      s += __expf(x - m);
    }
  }
#pragma unroll
  for (int off = 32; off; off >>= 1) {
    float mo = __shfl_xor(m, off), so = __shfl_xor(s, off);
    lse_comb(m, s, mo, so);
  }
  __shared__ float ms[4], ss[4];
  if ((tid & 63) == 0) { ms[tid >> 6] = m; ss[tid >> 6] = s; }
  __syncthreads();
  float M = ms[0], S = ss[0];
  for (int w2 = 1; w2 < 4; ++w2) lse_comb(M, S, ms[w2], ss[w2]);
  float logden = M + logf(S);
  for (int v = tid; v < V_; v += 256) dout[base + v] -= logden;
}

// ---------------- host launcher ----------------
extern "C" void kernel_launch(void* const* d_in, const int* in_sizes, int n_in,
                              void* d_out, int out_size, void* d_ws, size_t ws_size,
                              hipStream_t stream) {
  (void)in_sizes; (void)n_in; (void)out_size;
  const int* input = (const int*)d_in[0];
  const float* memory = (const float*)d_in[1];
  const float* enc = (const float*)d_in[2];
  const int* xs_len = (const int*)d_in[3];
  const float* emb = (const float*)d_in[4];
  const float* wih = (const float*)d_in[5];
  const float* whh = (const float*)d_in[6];
  const float* bih = (const float*)d_in[7];
  const float* bhh = (const float*)d_in[8];
  const float* l1 = (const float*)d_in[9];
  const float* l2 = (const float*)d_in[10];
  const float* wout = (const float*)d_in[11];
  const float* bout = (const float*)d_in[12];
  float* out = (float*)d_out;
  char* w = (char*)d_ws;

  size_t off = 0;
  auto alloc = [&](size_t bytes) {
    size_t o = off;
    off = (off + bytes + 255) & ~(size_t)255;
    return o;
  };
  const size_t N_WIH = 3072UL * 2048, N_WHH = 3072UL * 1024, N_L2 = 1024UL * 2048;
  const size_t N_L1 = 1024UL * 1024, N_ENC = 4096UL * 1024, N_WOUT = 32000UL * 1024;
  const size_t N_EMBX = 2048UL * 1024, N_ENCT = 4096UL * 1024, N_CTX = 33UL * 65536;
  const size_t N_EMBI = 2048UL * 3072;

  size_t o_wih_h = alloc(2 * N_WIH), o_wih_l = alloc(2 * N_WIH);
  size_t o_whh_h = alloc(2 * N_WHH), o_whh_l = alloc(2 * N_WHH);
  size_t o_l2_h = alloc(2 * N_L2), o_l2_l = alloc(2 * N_L2);
  size_t o_l1t_h = alloc(2 * N_L1), o_l1t_l = alloc(2 * N_L1);
  size_t o_enc_h = alloc(2 * N_ENC), o_enc_l = alloc(2 * N_ENC);
  size_t o_wout = alloc(2 * N_WOUT);
  size_t o_embx_h = alloc(2 * N_EMBX), o_embx_l = alloc(2 * N_EMBX);
  size_t o_encT = alloc(4 * N_ENCT);
  size_t o_embi = alloc(4 * N_EMBI);
  size_t o_ctx_h = alloc(2 * N_CTX), o_ctx_l = alloc(2 * N_CTX);
  size_t o_hf = alloc(4 * 65536), o_hh = alloc(2 * 65536), o_hl = alloc(2 * 65536);
  size_t o_cat_h = alloc(2 * 131072), o_cat_l = alloc(2 * 131072);
  size_t o_gip = alloc(4 * 2 * 196608), o_ghp = alloc(4 * 2 * 196608);
  size_t o_ctxp = alloc(4 * 4 * 65536);
  size_t o_bar = alloc(16384);

  if (off > ws_size) {
    k_guard<<<1, 1, 0, stream>>>(out, 1.0e8f + (float)(ws_size >> 20));
    return;
  }

  u16* wih_h = (u16*)(w + o_wih_h);   u16* wih_l = (u16*)(w + o_wih_l);
  u16* whh_h = (u16*)(w + o_whh_h);   u16* whh_l = (u16*)(w + o_whh_l);
  u16* l2_h = (u16*)(w + o_l2_h);     u16* l2_l = (u16*)(w + o_l2_l);
  u16* l1t_h = (u16*)(w + o_l1t_h);   u16* l1t_l = (u16*)(w + o_l1t_l);
  u16* enc_h = (u16*)(w + o_enc_h);   u16* enc_l = (u16*)(w + o_enc_l);
  u16* wout_b = (u16*)(w + o_wout);
  u16* embx_h = (u16*)(w + o_embx_h); u16* embx_l = (u16*)(w + o_embx_l);
  float* encT = (float*)(w + o_encT);
  float* embi = (float*)(w + o_embi);
  u16* ctx_h = (u16*)(w + o_ctx_h);   u16* ctx_l = (u16*)(w + o_ctx_l);
  float* hf = (float*)(w + o_hf);
  u16* hh = (u16*)(w + o_hh);         u16* hl = (u16*)(w + o_hl);
  u16* cat_h = (u16*)(w + o_cat_h);   u16* cat_l = (u16*)(w + o_cat_l);
  float* gip = (float*)(w + o_gip);
  float* ghp = (float*)(w + o_ghp);
  float* ctxp = (float*)(w + o_ctxp);
  unsigned* flags = (unsigned*)(w + o_bar);

  // prep
  k_split<<<2048, 256, 0, stream>>>(wih, wih_h, wih_l, (int)N_WIH);
  k_split<<<2048, 256, 0, stream>>>(whh, whh_h, whh_l, (int)N_WHH);
  k_split<<<2048, 256, 0, stream>>>(l2, l2_h, l2_l, (int)N_L2);
  k_split<<<2048, 256, 0, stream>>>(enc, enc_h, enc_l, (int)N_ENC);
  k_l1t<<<256, 256, 0, stream>>>(l1, l1t_h, l1t_l);
  k_tobf<<<4096, 256, 0, stream>>>(wout, wout_b, (int)N_WOUT);
  k_embx<<<2048, 256, 0, stream>>>(input, emb, embx_h, embx_l);
  k_h0<<<256, 256, 0, stream>>>(memory, hf, hh, hl);
  hipMemsetAsync(ctx_h, 0, 131072, stream);  // dctx slot 0 = zeros
  hipMemsetAsync(ctx_l, 0, 131072, stream);
  hipMemsetAsync(flags, 0, 16384, stream);   // barrier state (reset every launch)

  // encT = enc @ l1  (split-bf16)
  k_gemm128<1, 0><<<256, 256, 0, stream>>>(enc_h, enc_l, l1t_h, l1t_l, encT, nullptr,
                                           32, 8, 1024, 1024, 1024, 1024);
  // embi = embx @ w_ih[:, :1024]^T  (split-bf16): M=2048, N=3072, K=1024
  k_gemm128<1, 0><<<384, 256, 0, stream>>>(embx_h, embx_l, wih_h, wih_l, embi, nullptr,
                                           16, 24, 1024, 1024, 2048, 3072);

  // persistent recurrence
  k_rec<<<NB_, 256, 0, stream>>>(embi, ctx_h, ctx_l, hh, hl, hf,
                                 wih_h, wih_l, whh_h, whh_l, l2_h, l2_l,
                                 cat_h, cat_l, gip, ghp, ctxp, encT, enc, xs_len,
                                 bih, bhh, out, flags);

  // logits = dctx_all @ w_out^T + b_out, scattered to [b][t][v]
  k_gemm128<0, 1><<<4000, 256, 0, stream>>>(ctx_h + 65536, nullptr, wout_b, nullptr,
                                            out, bout, 16, 250, 1024, 1024, 1024, 0);
  // in-place log-softmax per (b,t) row
  k_lsm<<<2048, 256, 0, stream>>>(out);
}